// Round 1
// baseline (325.529 us; speedup 1.0000x reference)
//
#include <hip/hip_runtime.h>
#include <math.h>

#define HDIM 4096
#define NBLK 128
#define RNK  4
#define TOPK 3

// One workgroup (256 threads) per token. Fully fused:
// h = x + temb  -> coords = h@Wp + bp -> gaussian scores vs centers ->
// top-3 + softmax -> z_k = h @ A[n_k] (rank 4) -> delta = gate_k * z_k @ Bm[n_k]
// -> out = x + scale * delta (delta only touches 3 x 32 columns).
__global__ __launch_bounds__(256) void npl_fused(
    const float* __restrict__ x,
    const int*   __restrict__ task_ids,
    const float* __restrict__ task_emb,
    const float* __restrict__ Wp,
    const float* __restrict__ bp,
    const float* __restrict__ centers,
    const float* __restrict__ A,
    const float* __restrict__ Bm,
    const float* __restrict__ scale_p,
    float* __restrict__ out,
    int S_per_batch)
{
    __shared__ float h_lds[HDIM];
    __shared__ float red[4][16];
    __shared__ float sc[NBLK];
    __shared__ float zf[TOPK * RNK];
    __shared__ int   top_i[TOPK];
    __shared__ float gate[TOPK];
    __shared__ float dblk[TOPK * 32];
    __shared__ float coords_s[3];

    const int tid  = threadIdx.x;
    const int wid  = tid >> 6;
    const int lane = tid & 63;
    const int token = blockIdx.x;
    const int b = token / S_per_batch;
    const int task = task_ids[b];

    const float* xrow = x + (size_t)token * HDIM;
    const float* trow = task_emb + (size_t)task * HDIM;
    float*       orow = out + (size_t)token * HDIM;

    // ---- stage h into LDS (float4 mapping), keep x in regs, coords partials ----
    float4 xv[4];
    float c0 = 0.f, c1 = 0.f, c2 = 0.f;
#pragma unroll
    for (int k = 0; k < 4; ++k) {
        int i4 = tid + k * 256;
        float4 xx = reinterpret_cast<const float4*>(xrow)[i4];
        float4 tt = reinterpret_cast<const float4*>(trow)[i4];
        xv[k] = xx;
        float4 hh;
        hh.x = xx.x + tt.x; hh.y = xx.y + tt.y;
        hh.z = xx.z + tt.z; hh.w = xx.w + tt.w;
        reinterpret_cast<float4*>(h_lds)[i4] = hh;
        int e = i4 * 4;                     // element index of hh.x
        const float* wrow = Wp + (size_t)e * 3;   // 12 consecutive floats (16B aligned)
        c0 += hh.x * wrow[0];  c1 += hh.x * wrow[1];  c2 += hh.x * wrow[2];
        c0 += hh.y * wrow[3];  c1 += hh.y * wrow[4];  c2 += hh.y * wrow[5];
        c0 += hh.z * wrow[6];  c1 += hh.z * wrow[7];  c2 += hh.z * wrow[8];
        c0 += hh.w * wrow[9];  c1 += hh.w * wrow[10]; c2 += hh.w * wrow[11];
    }
    // wave reduce the 3 coord partials
#pragma unroll
    for (int off = 32; off; off >>= 1) {
        c0 += __shfl_down(c0, off);
        c1 += __shfl_down(c1, off);
        c2 += __shfl_down(c2, off);
    }
    if (lane == 0) { red[wid][0] = c0; red[wid][1] = c1; red[wid][2] = c2; }
    __syncthreads();
    if (tid == 0) {
        coords_s[0] = red[0][0] + red[1][0] + red[2][0] + red[3][0] + bp[0];
        coords_s[1] = red[0][1] + red[1][1] + red[2][1] + red[3][1] + bp[1];
        coords_s[2] = red[0][2] + red[1][2] + red[2][2] + red[3][2] + bp[2];
    }
    __syncthreads();

    // ---- scores vs 128 centers ----
    if (tid < NBLK) {
        float dx = coords_s[0] - centers[tid * 3 + 0];
        float dy = coords_s[1] - centers[tid * 3 + 1];
        float dz = coords_s[2] - centers[tid * 3 + 2];
        sc[tid] = -0.5f * (dx * dx + dy * dy + dz * dz);
    }
    __syncthreads();

    // ---- top-3 (wave 0), tie -> lowest index, then softmax gates ----
    if (wid == 0) {
        float v1 = sc[lane];
        float v2 = sc[lane + 64];
#pragma unroll
        for (int kk = 0; kk < TOPK; ++kk) {
            float v = v1; int idx = lane;
            if (v2 > v || (v2 == v && (lane + 64) < idx)) { v = v2; idx = lane + 64; }
#pragma unroll
            for (int off = 32; off; off >>= 1) {
                float ov = __shfl_down(v, off);
                int   oi = __shfl_down(idx, off);
                if (ov > v || (ov == v && oi < idx)) { v = ov; idx = oi; }
            }
            idx = __shfl(idx, 0);
            v   = __shfl(v, 0);
            if (lane == 0) { top_i[kk] = idx; gate[kk] = v; }
            // mask chosen index in-register (no LDS RAW hazard)
            if (idx == lane)      v1 = -3.0e38f;
            if (idx == lane + 64) v2 = -3.0e38f;
        }
        if (lane == 0) {
            float m  = gate[0];                    // max (sorted desc)
            float e0 = 1.0f;
            float e1 = expf(gate[1] - m);
            float e2 = expf(gate[2] - m);
            float inv = 1.0f / (e0 + e1 + e2);
            float s = scale_p[0];
            gate[0] = e0 * inv * s;
            gate[1] = e1 * inv * s;
            gate[2] = e2 * inv * s;
        }
    }
    __syncthreads();

    // ---- z_k = h @ A[n_k]  (coalesced float4 reads of A) ----
    float zp[TOPK][RNK];
#pragma unroll
    for (int kk = 0; kk < TOPK; ++kk)
#pragma unroll
        for (int r = 0; r < RNK; ++r) zp[kk][r] = 0.f;

#pragma unroll
    for (int kk = 0; kk < TOPK; ++kk) {
        int n = top_i[kk];
        const float4* Arow = reinterpret_cast<const float4*>(A + (size_t)n * HDIM * RNK);
#pragma unroll 4
        for (int k = 0; k < 16; ++k) {
            int i = tid + k * 256;
            float4 a = Arow[i];     // A[n][i][0..3]
            float hv = h_lds[i];
            zp[kk][0] += hv * a.x;
            zp[kk][1] += hv * a.y;
            zp[kk][2] += hv * a.z;
            zp[kk][3] += hv * a.w;
        }
    }
    // reduce 12 partials
#pragma unroll
    for (int off = 32; off; off >>= 1) {
#pragma unroll
        for (int kk = 0; kk < TOPK; ++kk)
#pragma unroll
            for (int r = 0; r < RNK; ++r)
                zp[kk][r] += __shfl_down(zp[kk][r], off);
    }
    if (lane == 0) {
#pragma unroll
        for (int kk = 0; kk < TOPK; ++kk)
#pragma unroll
            for (int r = 0; r < RNK; ++r)
                red[wid][kk * RNK + r] = zp[kk][r];
    }
    __syncthreads();
    if (tid < TOPK * RNK)
        zf[tid] = red[0][tid] + red[1][tid] + red[2][tid] + red[3][tid];
    __syncthreads();

    // ---- delta_blk = gate_k * (z_k @ Bm[n_k]) ----
    if (tid < TOPK * 32) {
        int kk = tid >> 5, c = tid & 31;
        int n = top_i[kk];
        const float* bm = Bm + (size_t)n * RNK * 32;
        float d = zf[kk * 4 + 0] * bm[c]
                + zf[kk * 4 + 1] * bm[32 + c]
                + zf[kk * 4 + 2] * bm[64 + c]
                + zf[kk * 4 + 3] * bm[96 + c];
        dblk[tid] = d * gate[kk];
    }
    __syncthreads();

    // ---- out = x + delta (delta only in the 3 selected 32-wide slices) ----
    int n0 = top_i[0], n1 = top_i[1], n2 = top_i[2];
#pragma unroll
    for (int k = 0; k < 4; ++k) {
        int i4 = tid + k * 256;
        int e = i4 * 4;          // all 4 elements fall in the same 32-block
        int bb = e >> 5;
        float4 o = xv[k];
        int base = -1;
        if (bb == n0) base = 0 * 32 + (e & 31);
        else if (bb == n1) base = 1 * 32 + (e & 31);
        else if (bb == n2) base = 2 * 32 + (e & 31);
        if (base >= 0) {
            o.x += dblk[base + 0];
            o.y += dblk[base + 1];
            o.z += dblk[base + 2];
            o.w += dblk[base + 3];
        }
        reinterpret_cast<float4*>(orow)[i4] = o;
    }
}

extern "C" void kernel_launch(void* const* d_in, const int* in_sizes, int n_in,
                              void* d_out, int out_size, void* d_ws, size_t ws_size,
                              hipStream_t stream) {
    const float* x        = (const float*)d_in[0];
    const int*   task_ids = (const int*)  d_in[1];
    const float* task_emb = (const float*)d_in[2];
    const float* Wp       = (const float*)d_in[3];
    const float* bp       = (const float*)d_in[4];
    const float* centers  = (const float*)d_in[5];
    const float* A        = (const float*)d_in[6];
    const float* Bm       = (const float*)d_in[7];
    const float* scale    = (const float*)d_in[8];

    int tokens = in_sizes[0] / HDIM;   // B*S
    int B      = in_sizes[1];
    int S      = tokens / B;

    npl_fused<<<dim3(tokens), dim3(256), 0, stream>>>(
        x, task_ids, task_emb, Wp, bp, centers, A, Bm, scale,
        (float*)d_out, S);
}

// Round 2
// 305.368 us; speedup vs baseline: 1.0660x; 1.0660x over previous
//
#include <hip/hip_runtime.h>
#include <math.h>

#define HDIM 4096
#define NBLK 128
#define RNK  4
#define TOPK 3

typedef float f4 __attribute__((ext_vector_type(4)));

// One workgroup (256 threads) per token. Fully fused:
// h = x + temb  -> coords = h@Wp + bp -> gaussian scores vs centers ->
// top-3 + softmax -> z_k = h @ A[n_k] (rank 4) -> delta = gate_k * z_k @ Bm[n_k]
// -> out = x + scale * delta (delta only touches 3 x 32 columns).
// x loads and out stores are NON-TEMPORAL so the 0.5 GB of streaming traffic
// doesn't evict the 8 MB A table (kept hot in L2/L3 for its 3 GB of re-reads).
__global__ __launch_bounds__(256) void npl_fused(
    const float* __restrict__ x,
    const int*   __restrict__ task_ids,
    const float* __restrict__ task_emb,
    const float* __restrict__ Wp,
    const float* __restrict__ bp,
    const float* __restrict__ centers,
    const float* __restrict__ A,
    const float* __restrict__ Bm,
    const float* __restrict__ scale_p,
    float* __restrict__ out,
    int S_per_batch)
{
    __shared__ float h_lds[HDIM];
    __shared__ float red[4][16];
    __shared__ float sc[NBLK];
    __shared__ float zf[TOPK * RNK];
    __shared__ int   top_i[TOPK];
    __shared__ float gate[TOPK];
    __shared__ float dblk[TOPK * 32];
    __shared__ float coords_s[3];

    const int tid  = threadIdx.x;
    const int wid  = tid >> 6;
    const int lane = tid & 63;
    const int token = blockIdx.x;
    const int b = token / S_per_batch;
    const int task = task_ids[b];

    const float* xrow = x + (size_t)token * HDIM;
    const float* trow = task_emb + (size_t)task * HDIM;
    float*       orow = out + (size_t)token * HDIM;

    const f4* xr4 = reinterpret_cast<const f4*>(xrow);
    const f4* tr4 = reinterpret_cast<const f4*>(trow);
    f4*       or4 = reinterpret_cast<f4*>(orow);

    // ---- stage h into LDS, keep x in regs (nt loads), coords partials ----
    f4 xv[4];
    float c0 = 0.f, c1 = 0.f, c2 = 0.f;
#pragma unroll
    for (int k = 0; k < 4; ++k) {
        int i4 = tid + k * 256;
        f4 xx = __builtin_nontemporal_load(xr4 + i4);
        f4 tt = tr4[i4];
        xv[k] = xx;
        f4 hh = xx + tt;
        reinterpret_cast<f4*>(h_lds)[i4] = hh;
        int e = i4 * 4;                     // element index of hh.x
        const float* wrow = Wp + (size_t)e * 3;   // 12 consecutive floats
        c0 += hh.x * wrow[0];  c1 += hh.x * wrow[1];  c2 += hh.x * wrow[2];
        c0 += hh.y * wrow[3];  c1 += hh.y * wrow[4];  c2 += hh.y * wrow[5];
        c0 += hh.z * wrow[6];  c1 += hh.z * wrow[7];  c2 += hh.z * wrow[8];
        c0 += hh.w * wrow[9];  c1 += hh.w * wrow[10]; c2 += hh.w * wrow[11];
    }
    // wave reduce the 3 coord partials
#pragma unroll
    for (int off = 32; off; off >>= 1) {
        c0 += __shfl_down(c0, off);
        c1 += __shfl_down(c1, off);
        c2 += __shfl_down(c2, off);
    }
    if (lane == 0) { red[wid][0] = c0; red[wid][1] = c1; red[wid][2] = c2; }
    __syncthreads();
    if (tid == 0) {
        coords_s[0] = red[0][0] + red[1][0] + red[2][0] + red[3][0] + bp[0];
        coords_s[1] = red[0][1] + red[1][1] + red[2][1] + red[3][1] + bp[1];
        coords_s[2] = red[0][2] + red[1][2] + red[2][2] + red[3][2] + bp[2];
    }
    __syncthreads();

    // ---- scores vs 128 centers ----
    if (tid < NBLK) {
        float dx = coords_s[0] - centers[tid * 3 + 0];
        float dy = coords_s[1] - centers[tid * 3 + 1];
        float dz = coords_s[2] - centers[tid * 3 + 2];
        sc[tid] = -0.5f * (dx * dx + dy * dy + dz * dz);
    }
    __syncthreads();

    // ---- top-3 (wave 0), tie -> lowest index, then softmax gates ----
    if (wid == 0) {
        float v1 = sc[lane];
        float v2 = sc[lane + 64];
#pragma unroll
        for (int kk = 0; kk < TOPK; ++kk) {
            float v = v1; int idx = lane;
            if (v2 > v || (v2 == v && (lane + 64) < idx)) { v = v2; idx = lane + 64; }
#pragma unroll
            for (int off = 32; off; off >>= 1) {
                float ov = __shfl_down(v, off);
                int   oi = __shfl_down(idx, off);
                if (ov > v || (ov == v && oi < idx)) { v = ov; idx = oi; }
            }
            idx = __shfl(idx, 0);
            v   = __shfl(v, 0);
            if (lane == 0) { top_i[kk] = idx; gate[kk] = v; }
            if (idx == lane)      v1 = -3.0e38f;
            if (idx == lane + 64) v2 = -3.0e38f;
        }
        if (lane == 0) {
            float m  = gate[0];                    // max (sorted desc)
            float e0 = 1.0f;
            float e1 = expf(gate[1] - m);
            float e2 = expf(gate[2] - m);
            float inv = 1.0f / (e0 + e1 + e2);
            float s = scale_p[0];
            gate[0] = e0 * inv * s;
            gate[1] = e1 * inv * s;
            gate[2] = e2 * inv * s;
        }
    }
    __syncthreads();

    // ---- z_k = h @ A[n_k]  (coalesced float4 reads of A, cached) ----
    float zp[TOPK][RNK];
#pragma unroll
    for (int kk = 0; kk < TOPK; ++kk)
#pragma unroll
        for (int r = 0; r < RNK; ++r) zp[kk][r] = 0.f;

#pragma unroll
    for (int kk = 0; kk < TOPK; ++kk) {
        int n = top_i[kk];
        const f4* Arow = reinterpret_cast<const f4*>(A + (size_t)n * HDIM * RNK);
#pragma unroll 4
        for (int k = 0; k < 16; ++k) {
            int i = tid + k * 256;
            f4 a = Arow[i];     // A[n][i][0..3]
            float hv = h_lds[i];
            zp[kk][0] += hv * a.x;
            zp[kk][1] += hv * a.y;
            zp[kk][2] += hv * a.z;
            zp[kk][3] += hv * a.w;
        }
    }
    // reduce 12 partials
#pragma unroll
    for (int off = 32; off; off >>= 1) {
#pragma unroll
        for (int kk = 0; kk < TOPK; ++kk)
#pragma unroll
            for (int r = 0; r < RNK; ++r)
                zp[kk][r] += __shfl_down(zp[kk][r], off);
    }
    if (lane == 0) {
#pragma unroll
        for (int kk = 0; kk < TOPK; ++kk)
#pragma unroll
            for (int r = 0; r < RNK; ++r)
                red[wid][kk * RNK + r] = zp[kk][r];
    }
    __syncthreads();
    if (tid < TOPK * RNK)
        zf[tid] = red[0][tid] + red[1][tid] + red[2][tid] + red[3][tid];
    __syncthreads();

    // ---- delta_blk = gate_k * (z_k @ Bm[n_k]) ----
    if (tid < TOPK * 32) {
        int kk = tid >> 5, c = tid & 31;
        int n = top_i[kk];
        const float* bm = Bm + (size_t)n * RNK * 32;
        float d = zf[kk * 4 + 0] * bm[c]
                + zf[kk * 4 + 1] * bm[32 + c]
                + zf[kk * 4 + 2] * bm[64 + c]
                + zf[kk * 4 + 3] * bm[96 + c];
        dblk[tid] = d * gate[kk];
    }
    __syncthreads();

    // ---- out = x + delta (nt stores; delta only in 3 selected 32-slices) ----
    int n0 = top_i[0], n1 = top_i[1], n2 = top_i[2];
#pragma unroll
    for (int k = 0; k < 4; ++k) {
        int i4 = tid + k * 256;
        int e = i4 * 4;          // all 4 elements fall in the same 32-block
        int bb = e >> 5;
        f4 o = xv[k];
        int base = -1;
        if (bb == n0) base = 0 * 32 + (e & 31);
        else if (bb == n1) base = 1 * 32 + (e & 31);
        else if (bb == n2) base = 2 * 32 + (e & 31);
        if (base >= 0) {
            o.x += dblk[base + 0];
            o.y += dblk[base + 1];
            o.z += dblk[base + 2];
            o.w += dblk[base + 3];
        }
        __builtin_nontemporal_store(o, or4 + i4);
    }
}

extern "C" void kernel_launch(void* const* d_in, const int* in_sizes, int n_in,
                              void* d_out, int out_size, void* d_ws, size_t ws_size,
                              hipStream_t stream) {
    const float* x        = (const float*)d_in[0];
    const int*   task_ids = (const int*)  d_in[1];
    const float* task_emb = (const float*)d_in[2];
    const float* Wp       = (const float*)d_in[3];
    const float* bp       = (const float*)d_in[4];
    const float* centers  = (const float*)d_in[5];
    const float* A        = (const float*)d_in[6];
    const float* Bm       = (const float*)d_in[7];
    const float* scale    = (const float*)d_in[8];

    int tokens = in_sizes[0] / HDIM;   // B*S
    int B      = in_sizes[1];
    int S      = tokens / B;

    npl_fused<<<dim3(tokens), dim3(256), 0, stream>>>(
        x, task_ids, task_emb, Wp, bp, centers, A, Bm, scale,
        (float*)d_out, S);
}

// Round 3
// 231.196 us; speedup vs baseline: 1.4080x; 1.3208x over previous
//
#include <hip/hip_runtime.h>
#include <math.h>

#define HDIM 4096
#define NBLK 128
#define RNK  4
#define TOPK 3

typedef float f4 __attribute__((ext_vector_type(4)));
typedef float f2 __attribute__((ext_vector_type(2)));
typedef _Float16 h8 __attribute__((ext_vector_type(8)));

// ---- preprocessing: A (fp32, [NB][H][R]) -> fp16 copy in d_ws (4 MiB) ----
// Read-once stream (nt loads); 8 floats per thread.
__global__ __launch_bounds__(256) void convert_A(
    const float* __restrict__ A, _Float16* __restrict__ Ah)
{
    int i = blockIdx.x * 256 + threadIdx.x;            // half8 index
    const f4* src = reinterpret_cast<const f4*>(A);
    f4 a0 = __builtin_nontemporal_load(src + 2 * i);
    f4 a1 = __builtin_nontemporal_load(src + 2 * i + 1);
    h8 r;
    r[0] = (_Float16)a0.x; r[1] = (_Float16)a0.y;
    r[2] = (_Float16)a0.z; r[3] = (_Float16)a0.w;
    r[4] = (_Float16)a1.x; r[5] = (_Float16)a1.y;
    r[6] = (_Float16)a1.z; r[7] = (_Float16)a1.w;
    reinterpret_cast<h8*>(Ah)[i] = r;
}

// One workgroup (256 threads) per token. Fully fused:
// h = x + temb -> coords = h@Wp + bp -> gaussian scores vs centers ->
// top-3 + softmax -> z_k = h @ A[n_k] (rank 4) -> delta = gate_k * z_k @ Bm[n_k]
// -> out = x + scale * delta. x/out are non-temporal (zero reuse).
// FP16A: A read from the fp16 L2-resident copy (4 MiB = one XCD L2).
template<bool FP16A>
__global__ __launch_bounds__(256) void npl_fused(
    const float* __restrict__ x,
    const int*   __restrict__ task_ids,
    const float* __restrict__ task_emb,
    const float* __restrict__ Wp,
    const float* __restrict__ bp,
    const float* __restrict__ centers,
    const float* __restrict__ A,
    const _Float16* __restrict__ Ah,
    const float* __restrict__ Bm,
    const float* __restrict__ scale_p,
    float* __restrict__ out,
    int S_per_batch)
{
    __shared__ float h_lds[HDIM];
    __shared__ float red[4][16];
    __shared__ float sc[NBLK];
    __shared__ float zf[TOPK * RNK];
    __shared__ int   top_i[TOPK];
    __shared__ float gate[TOPK];
    __shared__ float dblk[TOPK * 32];
    __shared__ float coords_s[3];

    const int tid  = threadIdx.x;
    const int wid  = tid >> 6;
    const int lane = tid & 63;
    const int token = blockIdx.x;
    const int b = token / S_per_batch;
    const int task = task_ids[b];

    const float* xrow = x + (size_t)token * HDIM;
    const float* trow = task_emb + (size_t)task * HDIM;
    float*       orow = out + (size_t)token * HDIM;

    const f4* xr4 = reinterpret_cast<const f4*>(xrow);
    const f4* tr4 = reinterpret_cast<const f4*>(trow);
    f4*       or4 = reinterpret_cast<f4*>(orow);

    // ---- stage h into LDS, keep x in regs (nt loads), coords partials ----
    f4 xv[4];
    float c0 = 0.f, c1 = 0.f, c2 = 0.f;
#pragma unroll
    for (int k = 0; k < 4; ++k) {
        int i4 = tid + k * 256;
        f4 xx = __builtin_nontemporal_load(xr4 + i4);
        f4 tt = tr4[i4];
        xv[k] = xx;
        f4 hh = xx + tt;
        reinterpret_cast<f4*>(h_lds)[i4] = hh;
        int e = i4 * 4;
        const float* wrow = Wp + (size_t)e * 3;   // 12 consecutive floats
        c0 += hh.x * wrow[0];  c1 += hh.x * wrow[1];  c2 += hh.x * wrow[2];
        c0 += hh.y * wrow[3];  c1 += hh.y * wrow[4];  c2 += hh.y * wrow[5];
        c0 += hh.z * wrow[6];  c1 += hh.z * wrow[7];  c2 += hh.z * wrow[8];
        c0 += hh.w * wrow[9];  c1 += hh.w * wrow[10]; c2 += hh.w * wrow[11];
    }
#pragma unroll
    for (int off = 32; off; off >>= 1) {
        c0 += __shfl_down(c0, off);
        c1 += __shfl_down(c1, off);
        c2 += __shfl_down(c2, off);
    }
    if (lane == 0) { red[wid][0] = c0; red[wid][1] = c1; red[wid][2] = c2; }
    __syncthreads();
    if (tid == 0) {
        coords_s[0] = red[0][0] + red[1][0] + red[2][0] + red[3][0] + bp[0];
        coords_s[1] = red[0][1] + red[1][1] + red[2][1] + red[3][1] + bp[1];
        coords_s[2] = red[0][2] + red[1][2] + red[2][2] + red[3][2] + bp[2];
    }
    __syncthreads();

    // ---- scores vs 128 centers ----
    if (tid < NBLK) {
        float dx = coords_s[0] - centers[tid * 3 + 0];
        float dy = coords_s[1] - centers[tid * 3 + 1];
        float dz = coords_s[2] - centers[tid * 3 + 2];
        sc[tid] = -0.5f * (dx * dx + dy * dy + dz * dz);
    }
    __syncthreads();

    // ---- top-3 (wave 0), tie -> lowest index, then softmax gates ----
    if (wid == 0) {
        float v1 = sc[lane];
        float v2 = sc[lane + 64];
#pragma unroll
        for (int kk = 0; kk < TOPK; ++kk) {
            float v = v1; int idx = lane;
            if (v2 > v || (v2 == v && (lane + 64) < idx)) { v = v2; idx = lane + 64; }
#pragma unroll
            for (int off = 32; off; off >>= 1) {
                float ov = __shfl_down(v, off);
                int   oi = __shfl_down(idx, off);
                if (ov > v || (ov == v && oi < idx)) { v = ov; idx = oi; }
            }
            idx = __shfl(idx, 0);
            v   = __shfl(v, 0);
            if (lane == 0) { top_i[kk] = idx; gate[kk] = v; }
            if (idx == lane)      v1 = -3.0e38f;
            if (idx == lane + 64) v2 = -3.0e38f;
        }
        if (lane == 0) {
            float m  = gate[0];
            float e0 = 1.0f;
            float e1 = expf(gate[1] - m);
            float e2 = expf(gate[2] - m);
            float inv = 1.0f / (e0 + e1 + e2);
            float s = scale_p[0];
            gate[0] = e0 * inv * s;
            gate[1] = e1 * inv * s;
            gate[2] = e2 * inv * s;
        }
    }
    __syncthreads();

    // ---- z_k = h @ A[n_k]  (rank 4) ----
    float zp[TOPK][RNK];
#pragma unroll
    for (int kk = 0; kk < TOPK; ++kk)
#pragma unroll
        for (int r = 0; r < RNK; ++r) zp[kk][r] = 0.f;

    if (FP16A) {
        // 16B loads: one half8 covers A[n][2j..2j+1][0..3]
#pragma unroll
        for (int kk = 0; kk < TOPK; ++kk) {
            int n = top_i[kk];
            const h8* Arow = reinterpret_cast<const h8*>(Ah + (size_t)n * HDIM * RNK);
#pragma unroll 4
            for (int j = 0; j < 8; ++j) {
                int idx = tid + j * 256;                  // covers i = 2*idx, 2*idx+1
                h8 a = Arow[idx];
                f2 hv = reinterpret_cast<const f2*>(h_lds)[idx];
                zp[kk][0] += hv.x * (float)a[0] + hv.y * (float)a[4];
                zp[kk][1] += hv.x * (float)a[1] + hv.y * (float)a[5];
                zp[kk][2] += hv.x * (float)a[2] + hv.y * (float)a[6];
                zp[kk][3] += hv.x * (float)a[3] + hv.y * (float)a[7];
            }
        }
    } else {
#pragma unroll
        for (int kk = 0; kk < TOPK; ++kk) {
            int n = top_i[kk];
            const f4* Arow = reinterpret_cast<const f4*>(A + (size_t)n * HDIM * RNK);
#pragma unroll 4
            for (int k = 0; k < 16; ++k) {
                int i = tid + k * 256;
                f4 a = Arow[i];
                float hv = h_lds[i];
                zp[kk][0] += hv * a.x;
                zp[kk][1] += hv * a.y;
                zp[kk][2] += hv * a.z;
                zp[kk][3] += hv * a.w;
            }
        }
    }
#pragma unroll
    for (int off = 32; off; off >>= 1) {
#pragma unroll
        for (int kk = 0; kk < TOPK; ++kk)
#pragma unroll
            for (int r = 0; r < RNK; ++r)
                zp[kk][r] += __shfl_down(zp[kk][r], off);
    }
    if (lane == 0) {
#pragma unroll
        for (int kk = 0; kk < TOPK; ++kk)
#pragma unroll
            for (int r = 0; r < RNK; ++r)
                red[wid][kk * RNK + r] = zp[kk][r];
    }
    __syncthreads();
    if (tid < TOPK * RNK)
        zf[tid] = red[0][tid] + red[1][tid] + red[2][tid] + red[3][tid];
    __syncthreads();

    // ---- delta_blk = gate_k * (z_k @ Bm[n_k]) ----
    if (tid < TOPK * 32) {
        int kk = tid >> 5, c = tid & 31;
        int n = top_i[kk];
        const float* bm = Bm + (size_t)n * RNK * 32;
        float d = zf[kk * 4 + 0] * bm[c]
                + zf[kk * 4 + 1] * bm[32 + c]
                + zf[kk * 4 + 2] * bm[64 + c]
                + zf[kk * 4 + 3] * bm[96 + c];
        dblk[tid] = d * gate[kk];
    }
    __syncthreads();

    // ---- out = x + delta (nt stores) ----
    int n0 = top_i[0], n1 = top_i[1], n2 = top_i[2];
#pragma unroll
    for (int k = 0; k < 4; ++k) {
        int i4 = tid + k * 256;
        int e = i4 * 4;
        int bb = e >> 5;
        f4 o = xv[k];
        int base = -1;
        if (bb == n0) base = 0 * 32 + (e & 31);
        else if (bb == n1) base = 1 * 32 + (e & 31);
        else if (bb == n2) base = 2 * 32 + (e & 31);
        if (base >= 0) {
            o.x += dblk[base + 0];
            o.y += dblk[base + 1];
            o.z += dblk[base + 2];
            o.w += dblk[base + 3];
        }
        __builtin_nontemporal_store(o, or4 + i4);
    }
}

extern "C" void kernel_launch(void* const* d_in, const int* in_sizes, int n_in,
                              void* d_out, int out_size, void* d_ws, size_t ws_size,
                              hipStream_t stream) {
    const float* x        = (const float*)d_in[0];
    const int*   task_ids = (const int*)  d_in[1];
    const float* task_emb = (const float*)d_in[2];
    const float* Wp       = (const float*)d_in[3];
    const float* bp       = (const float*)d_in[4];
    const float* centers  = (const float*)d_in[5];
    const float* A        = (const float*)d_in[6];
    const float* Bm       = (const float*)d_in[7];
    const float* scale    = (const float*)d_in[8];

    int tokens = in_sizes[0] / HDIM;   // B*S
    int B      = in_sizes[1];
    int S      = tokens / B;

    const size_t A_elems = (size_t)NBLK * HDIM * RNK;        // 2,097,152
    const size_t need    = A_elems * sizeof(_Float16);       // 4 MiB

    if (ws_size >= need) {
        _Float16* Ah = (_Float16*)d_ws;
        convert_A<<<dim3((int)(A_elems / 8 / 256)), dim3(256), 0, stream>>>(A, Ah);
        npl_fused<true><<<dim3(tokens), dim3(256), 0, stream>>>(
            x, task_ids, task_emb, Wp, bp, centers, A, Ah, Bm, scale,
            (float*)d_out, S);
    } else {
        npl_fused<false><<<dim3(tokens), dim3(256), 0, stream>>>(
            x, task_ids, task_emb, Wp, bp, centers, A, (const _Float16*)d_ws, Bm, scale,
            (float*)d_out, S);
    }
}

// Round 7
// 228.910 us; speedup vs baseline: 1.4221x; 1.0100x over previous
//
#include <hip/hip_runtime.h>
#include <math.h>

#define HDIM 4096
#define NBLK 128
#define RNK  4
#define TOPK 3

typedef float f4 __attribute__((ext_vector_type(4)));
typedef float f2 __attribute__((ext_vector_type(2)));
typedef _Float16 h8 __attribute__((ext_vector_type(8)));

// ---- preprocessing (VERBATIM round 3, passed): A fp32 -> fp16 copy ----
__global__ __launch_bounds__(256) void convert_A(
    const float* __restrict__ A, _Float16* __restrict__ Ah)
{
    int i = blockIdx.x * 256 + threadIdx.x;            // half8 index
    const f4* src = reinterpret_cast<const f4*>(A);
    f4 a0 = __builtin_nontemporal_load(src + 2 * i);
    f4 a1 = __builtin_nontemporal_load(src + 2 * i + 1);
    h8 r;
    r[0] = (_Float16)a0.x; r[1] = (_Float16)a0.y;
    r[2] = (_Float16)a0.z; r[3] = (_Float16)a0.w;
    r[4] = (_Float16)a1.x; r[5] = (_Float16)a1.y;
    r[6] = (_Float16)a1.z; r[7] = (_Float16)a1.w;
    reinterpret_cast<h8*>(Ah)[i] = r;
}

// One workgroup (256 threads) per token. Arithmetic is BIT-IDENTICAL to the
// passing round-3 kernel (same loops, same reduction trees, same left-assoc
// cross-wave sums, same score/gate/z/delta expressions, same fp16 A table).
// Structural changes only:
//  - coords finalize computed redundantly by EVERY thread (same bits)
//  - top-3 + gates run redundantly on EVERY wave in registers (argmax exact)
//  - zf summed per-thread from LDS partials (same association)
//  - delta recomputed in-register in the out phase (same expression)
//  => barriers: 7 -> 2; no serial single-thread/single-wave phases.
template<bool FP16A>
__global__ __launch_bounds__(256) void npl_fused(
    const float* __restrict__ x,
    const int*   __restrict__ task_ids,
    const float* __restrict__ task_emb,
    const float* __restrict__ Wp,
    const float* __restrict__ bp,
    const float* __restrict__ centers,
    const float* __restrict__ A,
    const _Float16* __restrict__ Ah,
    const float* __restrict__ Bm,
    const float* __restrict__ scale_p,
    float* __restrict__ out,
    int S_per_batch)
{
    __shared__ float h_lds[HDIM];
    __shared__ float redc[4][4];    // per-wave coords partials (separate from redz!)
    __shared__ float redz[4][12];   // per-wave z partials

    const int tid  = threadIdx.x;
    const int wid  = tid >> 6;
    const int lane = tid & 63;
    const int token = blockIdx.x;
    const int b = token / S_per_batch;
    const int task = task_ids[b];

    const float* xrow = x + (size_t)token * HDIM;
    const float* trow = task_emb + (size_t)task * HDIM;
    float*       orow = out + (size_t)token * HDIM;

    const f4* xr4 = reinterpret_cast<const f4*>(xrow);
    const f4* tr4 = reinterpret_cast<const f4*>(trow);
    f4*       or4 = reinterpret_cast<f4*>(orow);

    // ---- phase 1 (verbatim r3): stage h to LDS, x in regs, coords partials ----
    f4 xv[4];
    float c0 = 0.f, c1 = 0.f, c2 = 0.f;
#pragma unroll
    for (int k = 0; k < 4; ++k) {
        int i4 = tid + k * 256;
        f4 xx = __builtin_nontemporal_load(xr4 + i4);
        f4 tt = tr4[i4];
        xv[k] = xx;
        f4 hh = xx + tt;
        reinterpret_cast<f4*>(h_lds)[i4] = hh;
        int e = i4 * 4;
        const float* wrow = Wp + (size_t)e * 3;   // 12 consecutive floats
        c0 += hh.x * wrow[0];  c1 += hh.x * wrow[1];  c2 += hh.x * wrow[2];
        c0 += hh.y * wrow[3];  c1 += hh.y * wrow[4];  c2 += hh.y * wrow[5];
        c0 += hh.z * wrow[6];  c1 += hh.z * wrow[7];  c2 += hh.z * wrow[8];
        c0 += hh.w * wrow[9];  c1 += hh.w * wrow[10]; c2 += hh.w * wrow[11];
    }
#pragma unroll
    for (int off = 32; off; off >>= 1) {
        c0 += __shfl_down(c0, off);
        c1 += __shfl_down(c1, off);
        c2 += __shfl_down(c2, off);
    }
    if (lane == 0) { redc[wid][0] = c0; redc[wid][1] = c1; redc[wid][2] = c2; }
    __syncthreads();   // barrier 1 of 2

    // ---- coords finalize: every thread, r3's exact left-assoc sum ----
    c0 = redc[0][0] + redc[1][0] + redc[2][0] + redc[3][0] + bp[0];
    c1 = redc[0][1] + redc[1][1] + redc[2][1] + redc[3][1] + bp[1];
    c2 = redc[0][2] + redc[1][2] + redc[2][2] + redc[3][2] + bp[2];

    // ---- scores for blocks `lane` and `lane+64` (r3 expression) ----
    float dx = c0 - centers[lane * 3 + 0];
    float dy = c1 - centers[lane * 3 + 1];
    float dz = c2 - centers[lane * 3 + 2];
    float v1 = -0.5f * (dx * dx + dy * dy + dz * dz);
    dx = c0 - centers[(lane + 64) * 3 + 0];
    dy = c1 - centers[(lane + 64) * 3 + 1];
    dz = c2 - centers[(lane + 64) * 3 + 2];
    float v2 = -0.5f * (dx * dx + dy * dy + dz * dz);

    // ---- top-3 (r3 loop verbatim, run redundantly on every wave) ----
    float tv0, tv1, tv2; int n0, n1, n2;
#pragma unroll
    for (int kk = 0; kk < TOPK; ++kk) {
        float v = v1; int idx = lane;
        if (v2 > v || (v2 == v && (lane + 64) < idx)) { v = v2; idx = lane + 64; }
#pragma unroll
        for (int off = 32; off; off >>= 1) {
            float ov = __shfl_down(v, off);
            int   oi = __shfl_down(idx, off);
            if (ov > v || (ov == v && oi < idx)) { v = ov; idx = oi; }
        }
        idx = __shfl(idx, 0);
        v   = __shfl(v, 0);
        if (kk == 0)      { tv0 = v; n0 = idx; }
        else if (kk == 1) { tv1 = v; n1 = idx; }
        else              { tv2 = v; n2 = idx; }
        if (idx == lane)      v1 = -3.0e38f;
        if (idx == lane + 64) v2 = -3.0e38f;
    }

    // ---- gates (r3 op sequence, all lanes — values are wave-uniform) ----
    float m  = tv0;
    float e0 = 1.0f;
    float e1 = expf(tv1 - m);
    float e2 = expf(tv2 - m);
    float inv = 1.0f / (e0 + e1 + e2);
    float s = scale_p[0];
    float g0 = e0 * inv * s;
    float g1 = e1 * inv * s;
    float g2 = e2 * inv * s;

    // ---- z_k = h @ A[n_k]  (verbatim r3 fp16/fp32 paths) ----
    float zp[TOPK][RNK];
#pragma unroll
    for (int kk = 0; kk < TOPK; ++kk)
#pragma unroll
        for (int r = 0; r < RNK; ++r) zp[kk][r] = 0.f;

    if (FP16A) {
#pragma unroll
        for (int kk = 0; kk < TOPK; ++kk) {
            int n = (kk == 0) ? n0 : (kk == 1) ? n1 : n2;
            const h8* Arow = reinterpret_cast<const h8*>(Ah + (size_t)n * HDIM * RNK);
#pragma unroll 4
            for (int j = 0; j < 8; ++j) {
                int idx = tid + j * 256;
                h8 a = Arow[idx];
                f2 hv = reinterpret_cast<const f2*>(h_lds)[idx];
                zp[kk][0] += hv.x * (float)a[0] + hv.y * (float)a[4];
                zp[kk][1] += hv.x * (float)a[1] + hv.y * (float)a[5];
                zp[kk][2] += hv.x * (float)a[2] + hv.y * (float)a[6];
                zp[kk][3] += hv.x * (float)a[3] + hv.y * (float)a[7];
            }
        }
    } else {
#pragma unroll
        for (int kk = 0; kk < TOPK; ++kk) {
            int n = (kk == 0) ? n0 : (kk == 1) ? n1 : n2;
            const f4* Arow = reinterpret_cast<const f4*>(A + (size_t)n * HDIM * RNK);
#pragma unroll 4
            for (int k = 0; k < 16; ++k) {
                int i = tid + k * 256;
                f4 a = Arow[i];
                float hv = h_lds[i];
                zp[kk][0] += hv * a.x;
                zp[kk][1] += hv * a.y;
                zp[kk][2] += hv * a.z;
                zp[kk][3] += hv * a.w;
            }
        }
    }
#pragma unroll
    for (int off = 32; off; off >>= 1) {
#pragma unroll
        for (int kk = 0; kk < TOPK; ++kk)
#pragma unroll
            for (int r = 0; r < RNK; ++r)
                zp[kk][r] += __shfl_down(zp[kk][r], off);
    }
    if (lane == 0) {
#pragma unroll
        for (int kk = 0; kk < TOPK; ++kk)
#pragma unroll
            for (int r = 0; r < RNK; ++r)
                redz[wid][kk * RNK + r] = zp[kk][r];
    }
    __syncthreads();   // barrier 2 of 2

    // ---- zf: every thread, r3's exact left-assoc cross-wave sum ----
    float zf_[12];
#pragma unroll
    for (int t = 0; t < 12; ++t)
        zf_[t] = redz[0][t] + redz[1][t] + redz[2][t] + redz[3][t];

    // ---- out = x + delta (delta recomputed in-register, r3 expression) ----
#pragma unroll
    for (int k = 0; k < 4; ++k) {
        int i4 = tid + k * 256;
        int e = i4 * 4;          // all 4 elements fall in the same 32-block
        int bb = e >> 5;
        f4 o = xv[k];
        int kk = (bb == n0) ? 0 : (bb == n1) ? 1 : (bb == n2) ? 2 : -1;
        if (kk >= 0) {
            int nn = (kk == 0) ? n0 : (kk == 1) ? n1 : n2;
            float za = (kk == 0) ? zf_[0] : (kk == 1) ? zf_[4] : zf_[8];
            float zb = (kk == 0) ? zf_[1] : (kk == 1) ? zf_[5] : zf_[9];
            float zc = (kk == 0) ? zf_[2] : (kk == 1) ? zf_[6] : zf_[10];
            float zd = (kk == 0) ? zf_[3] : (kk == 1) ? zf_[7] : zf_[11];
            float gg = (kk == 0) ? g0 : (kk == 1) ? g1 : g2;
            const float* bm = Bm + (size_t)nn * 128;
            int c = e & 31;
            float d0 = za * bm[c + 0] + zb * bm[32 + c + 0] + zc * bm[64 + c + 0] + zd * bm[96 + c + 0];
            float d1 = za * bm[c + 1] + zb * bm[32 + c + 1] + zc * bm[64 + c + 1] + zd * bm[96 + c + 1];
            float d2 = za * bm[c + 2] + zb * bm[32 + c + 2] + zc * bm[64 + c + 2] + zd * bm[96 + c + 2];
            float d3 = za * bm[c + 3] + zb * bm[32 + c + 3] + zc * bm[64 + c + 3] + zd * bm[96 + c + 3];
            o.x += d0 * gg;
            o.y += d1 * gg;
            o.z += d2 * gg;
            o.w += d3 * gg;
        }
        __builtin_nontemporal_store(o, or4 + i4);
    }
}

extern "C" void kernel_launch(void* const* d_in, const int* in_sizes, int n_in,
                              void* d_out, int out_size, void* d_ws, size_t ws_size,
                              hipStream_t stream) {
    const float* x        = (const float*)d_in[0];
    const int*   task_ids = (const int*)  d_in[1];
    const float* task_emb = (const float*)d_in[2];
    const float* Wp       = (const float*)d_in[3];
    const float* bp       = (const float*)d_in[4];
    const float* centers  = (const float*)d_in[5];
    const float* A        = (const float*)d_in[6];
    const float* Bm       = (const float*)d_in[7];
    const float* scale    = (const float*)d_in[8];

    int tokens = in_sizes[0] / HDIM;   // B*S
    int B      = in_sizes[1];
    int S      = tokens / B;

    const size_t A_elems = (size_t)NBLK * HDIM * RNK;        // 2,097,152
    const size_t need    = A_elems * sizeof(_Float16);       // 4 MiB

    if (ws_size >= need) {
        _Float16* Ah = (_Float16*)d_ws;
        convert_A<<<dim3((int)(A_elems / 8 / 256)), dim3(256), 0, stream>>>(A, Ah);
        npl_fused<true><<<dim3(tokens), dim3(256), 0, stream>>>(
            x, task_ids, task_emb, Wp, bp, centers, A, Ah, Bm, scale,
            (float*)d_out, S);
    } else {
        npl_fused<false><<<dim3(tokens), dim3(256), 0, stream>>>(
            x, task_ids, task_emb, Wp, bp, centers, A, (const _Float16*)d_ws, Bm, scale,
            (float*)d_out, S);
    }
}